// Round 4
// baseline (193.796 us; speedup 1.0000x reference)
//
#include <hip/hip_runtime.h>
#include <math.h>

#define N_HEADS 8
#define N_LEVELS 4
#define N_POINTS 4
#define LQ 5440
#define LV 5440
#define BATCH_ 4
#define M_TOT (BATCH_ * LQ)   // 21760

typedef __bf16 bf16x8 __attribute__((ext_vector_type(8)));
typedef float f32x4 __attribute__((ext_vector_type(4)));
typedef unsigned int uint_t;

__device__ __forceinline__ unsigned short rne_bf16(float x) {
  uint_t u = __float_as_uint(x);
  uint_t r = u + 0x7fffu + ((u >> 16) & 1u);
  return (unsigned short)(r >> 16);
}
__device__ __forceinline__ float bf16_to_f(unsigned short h) {
  return __uint_as_float(((uint_t)h) << 16);
}

// ---------------- input conversion: query -> Q3 (hi|lo), input_flatten -> IFh ----------------
__global__ __launch_bounds__(256) void conv_inputs(
    const float* __restrict__ q, const float* __restrict__ iff,
    unsigned short* __restrict__ Q3, unsigned short* __restrict__ IFh)
{
  const int t = blockIdx.x * 256 + threadIdx.x;   // 0 .. M*64
  const int r = t >> 6;
  const int c = (t & 63) * 4;
  const float4 qa = *(const float4*)(q + (size_t)r * 256 + c);
  ushort4 h, l;
  {
    const float v[4] = {qa.x, qa.y, qa.z, qa.w};
    unsigned short hh[4], ll[4];
#pragma unroll
    for (int i = 0; i < 4; ++i) {
      hh[i] = rne_bf16(v[i]);
      ll[i] = rne_bf16(v[i] - bf16_to_f(hh[i]));
    }
    h = make_ushort4(hh[0], hh[1], hh[2], hh[3]);
    l = make_ushort4(ll[0], ll[1], ll[2], ll[3]);
  }
  *(ushort4*)(Q3 + (size_t)r * 512 + c) = h;
  *(ushort4*)(Q3 + (size_t)r * 512 + 256 + c) = l;
  const float4 fa = *(const float4*)(iff + (size_t)r * 256 + c);
  *(ushort4*)(IFh + (size_t)r * 256 + c) =
      make_ushort4(rne_bf16(fa.x), rne_bf16(fa.y), rne_bf16(fa.z), rne_bf16(fa.w));
}

// ---------------- weight conversion (transpose + bf16) ----------------
// mode 1 (2-term split): Wt2[n][0..255]=hi, [256..511]=hi  (pairs with A=[hi|lo])
// mode 0: Wt[n][0..255]=hi
__global__ __launch_bounds__(256) void conv_weights(
    const float* __restrict__ w_off, const float* __restrict__ w_out,
    const float* __restrict__ w_val, const float* __restrict__ w_attn,
    unsigned short* __restrict__ Woff2, unsigned short* __restrict__ Wo2,
    unsigned short* __restrict__ Wvt, unsigned short* __restrict__ Wat)
{
  __shared__ float tbuf[64][65];
  const int tid = threadIdx.x;
  const int k0 = blockIdx.x * 64;
  const int yy = blockIdx.y;
  const float* src; unsigned short* dst; int N; int mode; int ntile;
  if (yy < 4)       { src = w_off;  dst = Woff2; N = 256; mode = 1; ntile = yy; }
  else if (yy < 8)  { src = w_out;  dst = Wo2;   N = 256; mode = 1; ntile = yy - 4; }
  else if (yy < 12) { src = w_val;  dst = Wvt;   N = 256; mode = 0; ntile = yy - 8; }
  else              { src = w_attn; dst = Wat;   N = 128; mode = 0; ntile = yy - 12; }
  const int n0 = ntile * 64;
#pragma unroll
  for (int i = 0; i < 16; ++i) {
    const int r = (tid >> 6) + i * 4;
    const int c = tid & 63;
    tbuf[r][c] = src[(size_t)(k0 + r) * N + n0 + c];
  }
  __syncthreads();
#pragma unroll
  for (int i = 0; i < 16; ++i) {
    const int n = (tid >> 6) + i * 4;
    const int kk = tid & 63;
    const float v = tbuf[kk][n];
    const unsigned short h = rne_bf16(v);
    if (mode) {
      const size_t rowb = (size_t)(n0 + n) * 512;
      dst[rowb + k0 + kk] = h;
      dst[rowb + 256 + k0 + kk] = h;
    } else {
      dst[(size_t)(n0 + n) * 256 + k0 + kk] = h;
    }
  }
}

// ---------------- bf16 MFMA GEMM, m97 structure ----------------
template<int KSTEPS, int AMOD, bool OUT_BF16>
__global__ __launch_bounds__(256) void gemm_mfma(
    const unsigned short* __restrict__ A, int lda,
    const unsigned short* __restrict__ Bt,   // [N][KSTEPS*64]
    const float* __restrict__ bias,
    void* __restrict__ Cout, int ldc)
{
  constexpr int LDB = KSTEPS * 64;
  __shared__ unsigned short As[128 * 64];
  __shared__ unsigned short Bs[128 * 64];
  const int tid = threadIdx.x;
  const int w = tid >> 6, lane = tid & 63;
  const int wm = w >> 1, wn = w & 1;
  const int lr = lane & 15, lk = lane >> 4;
  const int m0 = blockIdx.y * 128, n0 = blockIdx.x * 128;

  f32x4 acc[4][4] = {};

  for (int t = 0; t < KSTEPS; ++t) {
    int ka = t * 64; if (ka >= AMOD) ka -= AMOD;
    const int kb = t * 64;
#pragma unroll
    for (int i = 0; i < 4; ++i) {
      const int rbase = i * 32 + w * 8;
      const int row = rbase + (lane >> 3);
      const int slot = lane & 7;
      const int gs = slot ^ (row & 7);                 // inverse-swizzle the SOURCE (rule 21)
      const unsigned short* gp = A + (size_t)(m0 + row) * lda + ka + gs * 8;
      __builtin_amdgcn_global_load_lds(
          (const __attribute__((address_space(1))) uint_t*)gp,
          (__attribute__((address_space(3))) uint_t*)(As + rbase * 64), 16, 0, 0);
    }
#pragma unroll
    for (int i = 0; i < 4; ++i) {
      const int rbase = i * 32 + w * 8;
      const int row = rbase + (lane >> 3);
      const int slot = lane & 7;
      const int gs = slot ^ (row & 7);
      const unsigned short* gp = Bt + (size_t)(n0 + row) * LDB + kb + gs * 8;
      __builtin_amdgcn_global_load_lds(
          (const __attribute__((address_space(1))) uint_t*)gp,
          (__attribute__((address_space(3))) uint_t*)(Bs + rbase * 64), 16, 0, 0);
    }
    asm volatile("s_waitcnt vmcnt(0)" ::: "memory");
    __syncthreads();
#pragma unroll
    for (int kk = 0; kk < 2; ++kk) {
      bf16x8 af[4], bfv[4];
#pragma unroll
      for (int m = 0; m < 4; ++m) {
        const int row = wm * 64 + m * 16 + lr;
        const int so = (kk * 4 + lk) ^ (row & 7);      // swizzled read
        af[m] = *(const bf16x8*)((const char*)As + row * 128 + so * 16);
      }
#pragma unroll
      for (int n = 0; n < 4; ++n) {
        const int row = wn * 64 + n * 16 + lr;
        const int so = (kk * 4 + lk) ^ (row & 7);
        bfv[n] = *(const bf16x8*)((const char*)Bs + row * 128 + so * 16);
      }
#pragma unroll
      for (int m = 0; m < 4; ++m)
#pragma unroll
        for (int n = 0; n < 4; ++n)
          acc[m][n] = __builtin_amdgcn_mfma_f32_16x16x32_bf16(af[m], bfv[n], acc[m][n], 0, 0, 0);
    }
    __syncthreads();
  }
#pragma unroll
  for (int n = 0; n < 4; ++n) {
    const int col = n0 + wn * 64 + n * 16 + lr;
    const float bv = bias[col];
#pragma unroll
    for (int m = 0; m < 4; ++m) {
      const int rbase = m0 + wm * 64 + m * 16 + lk * 4;
#pragma unroll
      for (int j = 0; j < 4; ++j) {
        const float v = acc[m][n][j] + bv;
        if (OUT_BF16) ((unsigned short*)Cout)[(size_t)(rbase + j) * ldc + col] = rne_bf16(v);
        else          ((float*)Cout)[(size_t)(rbase + j) * ldc + col] = v;
      }
    }
  }
}

// ---------------- sampler v4: level-per-lane ----------------
// 256 threads = 8 queries x 8 heads x 4 lanes(=levels). Each lane handles its own
// level's 4 points across ALL 32 head-channels; 4-lane shfl butterfly reduces.
template<int BASE>
__device__ __forceinline__ void write_slice(const float* acc, unsigned short* op) {
  unsigned short h8[8], l8[8];
#pragma unroll
  for (int i = 0; i < 8; ++i) {
    h8[i] = rne_bf16(acc[BASE + i]);
    l8[i] = rne_bf16(acc[BASE + i] - bf16_to_f(h8[i]));
  }
  *(ushort4*)(op)       = make_ushort4(h8[0], h8[1], h8[2], h8[3]);
  *(ushort4*)(op + 4)   = make_ushort4(h8[4], h8[5], h8[6], h8[7]);
  *(ushort4*)(op + 256) = make_ushort4(l8[0], l8[1], l8[2], l8[3]);
  *(ushort4*)(op + 260) = make_ushort4(l8[4], l8[5], l8[6], l8[7]);
}

__global__ __launch_bounds__(256) void msda_sample_v4(
    const float* __restrict__ off_buf,            // [M,256]
    const unsigned short* __restrict__ logit_buf, // [M,128] bf16
    const unsigned short* __restrict__ value,     // [B,LV,256] bf16
    const float* __restrict__ ref_pts,            // [B,LQ,4,2]
    const int*  __restrict__ sshapes, const int* __restrict__ lstart,
    unsigned short* __restrict__ samp3)           // [M,512]
{
  __shared__ float off_s[8][256];
  __shared__ float logit_s[8][128];
  __shared__ float ref_s[8][8];
  __shared__ int   shp_s[8];
  __shared__ int   st_s[4];
  const int tid = threadIdx.x;
  const int q0 = blockIdx.x * 8;

#pragma unroll
  for (int i = 0; i < 2; ++i) {
    const int j = tid + i * 256;
    const int qq = j >> 6, cc = (j & 63) * 4;
    *(float4*)&off_s[qq][cc] = *(const float4*)(off_buf + (size_t)(q0 + qq) * 256 + cc);
  }
  if (tid < 128) {
    const int qq = tid >> 4, cc = (tid & 15) * 8;
    const uint4 g = *(const uint4*)(logit_buf + (size_t)(q0 + qq) * 128 + cc);
    const uint_t u[4] = {g.x, g.y, g.z, g.w};
#pragma unroll
    for (int k = 0; k < 4; ++k) {
      logit_s[qq][cc + 2 * k]     = __uint_as_float(u[k] << 16);
      logit_s[qq][cc + 2 * k + 1] = __uint_as_float(u[k] & 0xffff0000u);
    }
  }
  if (tid < 64) ref_s[tid >> 3][tid & 7] = ref_pts[(size_t)(q0 + (tid >> 3)) * 8 + (tid & 7)];
  if (tid >= 64 && tid < 72) shp_s[tid - 64] = sshapes[tid - 64];
  if (tid >= 96 && tid < 100) st_s[tid - 96] = lstart[tid - 96];
  __syncthreads();

  const int q  = tid >> 5;        // 8 queries per block
  const int l5 = tid & 31;
  const int h  = l5 >> 2;
  const int lv = l5 & 3;          // this lane's level
  const int qg = q0 + q;
  const int b  = blockIdx.x / (LQ / 8);

  // 4-lane cooperative softmax over the head's 16 logits
  float lg[4];
#pragma unroll
  for (int p = 0; p < 4; ++p) lg[p] = logit_s[q][h * 16 + lv * 4 + p];
  float mx = fmaxf(fmaxf(lg[0], lg[1]), fmaxf(lg[2], lg[3]));
  mx = fmaxf(mx, __shfl_xor(mx, 1));
  mx = fmaxf(mx, __shfl_xor(mx, 2));
  float ex[4]; float ssum = 0.f;
#pragma unroll
  for (int p = 0; p < 4; ++p) { ex[p] = __expf(lg[p] - mx); ssum += ex[p]; }
  ssum += __shfl_xor(ssum, 1);
  ssum += __shfl_xor(ssum, 2);
  const float inv = 1.f / ssum;

  // own level geometry
  const int Hl = shp_s[2 * lv], Wl = shp_s[2 * lv + 1];
  const float fx = ref_s[q][2 * lv + 0] * (float)Wl - 0.5f;
  const float fy = ref_s[q][2 * lv + 1] * (float)Hl - 0.5f;
  const uint_t base_l = ((uint_t)b * LV + (uint_t)st_s[lv]) * 512u + (uint_t)h * 64u;
  const char* vbyte = (const char*)value;

  float acc[32] = {};

#define ACCUM8(J, U4, WV) {                                                        \
    const uint_t uu0 = (U4).x, uu1 = (U4).y, uu2 = (U4).z, uu3 = (U4).w;           \
    acc[(J)+0] = fmaf((WV), __uint_as_float(uu0 << 16),         acc[(J)+0]);       \
    acc[(J)+1] = fmaf((WV), __uint_as_float(uu0 & 0xffff0000u), acc[(J)+1]);       \
    acc[(J)+2] = fmaf((WV), __uint_as_float(uu1 << 16),         acc[(J)+2]);       \
    acc[(J)+3] = fmaf((WV), __uint_as_float(uu1 & 0xffff0000u), acc[(J)+3]);       \
    acc[(J)+4] = fmaf((WV), __uint_as_float(uu2 << 16),         acc[(J)+4]);       \
    acc[(J)+5] = fmaf((WV), __uint_as_float(uu2 & 0xffff0000u), acc[(J)+5]);       \
    acc[(J)+6] = fmaf((WV), __uint_as_float(uu3 << 16),         acc[(J)+6]);       \
    acc[(J)+7] = fmaf((WV), __uint_as_float(uu3 & 0xffff0000u), acc[(J)+7]); }

#define CORNER(VO, WV) {                                                           \
    const uint4* gp = (const uint4*)(vbyte + (VO));                                \
    const uint4 c0 = gp[0], c1 = gp[1], c2 = gp[2], c3 = gp[3];                    \
    ACCUM8(0, c0, WV); ACCUM8(8, c1, WV); ACCUM8(16, c2, WV); ACCUM8(24, c3, WV); }

#pragma unroll
  for (int p = 0; p < 4; ++p) {
    const float x = fx + off_s[q][h * 32 + lv * 8 + p * 2 + 0];
    const float y = fy + off_s[q][h * 32 + lv * 8 + p * 2 + 1];
    const float aw = ex[p] * inv;
    const float xf = floorf(x), yf = floorf(y);
    const int x0i = (int)xf, y0i = (int)yf;
    const float wx1 = x - xf, wy1 = y - yf;
    const float wx0 = 1.f - wx1, wy0 = 1.f - wy1;
    const int x1i = x0i + 1, y1i = y0i + 1;
    const bool vx0 = (uint_t)x0i < (uint_t)Wl, vx1 = (uint_t)x1i < (uint_t)Wl;
    const bool vy0 = (uint_t)y0i < (uint_t)Hl, vy1 = (uint_t)y1i < (uint_t)Hl;
    const int xc0 = min(max(x0i, 0), Wl - 1), xc1 = min(max(x1i, 0), Wl - 1);
    const int yc0 = min(max(y0i, 0), Hl - 1), yc1 = min(max(y1i, 0), Hl - 1);
    const float awy0 = aw * wy0, awy1 = aw * wy1;
    const float w00 = (vy0 && vx0) ? awy0 * wx0 : 0.f;
    const float w01 = (vy0 && vx1) ? awy0 * wx1 : 0.f;
    const float w10 = (vy1 && vx0) ? awy1 * wx0 : 0.f;
    const float w11 = (vy1 && vx1) ? awy1 * wx1 : 0.f;
    const int r0 = yc0 * Wl, r1 = yc1 * Wl;
    const uint_t vo00 = base_l + (uint_t)(r0 + xc0) * 512u;
    const uint_t vo01 = base_l + (uint_t)(r0 + xc1) * 512u;
    const uint_t vo10 = base_l + (uint_t)(r1 + xc0) * 512u;
    const uint_t vo11 = base_l + (uint_t)(r1 + xc1) * 512u;
    CORNER(vo00, w00);
    CORNER(vo01, w01);
    CORNER(vo10, w10);
    CORNER(vo11, w11);
  }

  // butterfly reduce across the 4 lanes of the (q,h) group
#pragma unroll
  for (int c = 0; c < 32; ++c) {
    acc[c] += __shfl_xor(acc[c], 1);
    acc[c] += __shfl_xor(acc[c], 2);
  }

  unsigned short* op = samp3 + (size_t)qg * 512 + h * 32 + lv * 8;
  switch (lv) {
    case 0: write_slice<0>(acc, op); break;
    case 1: write_slice<8>(acc, op); break;
    case 2: write_slice<16>(acc, op); break;
    default: write_slice<24>(acc, op); break;
  }
}

extern "C" void kernel_launch(void* const* d_in, const int* in_sizes, int n_in,
                              void* d_out, int out_size, void* d_ws, size_t ws_size,
                              hipStream_t stream) {
  const float* query         = (const float*)d_in[0];
  const float* ref_pts       = (const float*)d_in[1];
  const float* input_flatten = (const float*)d_in[2];
  const int*   sshapes       = (const int*)d_in[3];
  const int*   lstart        = (const int*)d_in[4];
  const float* w_val  = (const float*)d_in[5];
  const float* b_val  = (const float*)d_in[6];
  const float* w_off  = (const float*)d_in[7];
  const float* b_off  = (const float*)d_in[8];
  const float* w_attn = (const float*)d_in[9];
  const float* b_attn = (const float*)d_in[10];
  const float* w_out  = (const float*)d_in[11];
  const float* b_out  = (const float*)d_in[12];
  float* out = (float*)d_out;

  char* ws = (char*)d_ws;
  unsigned short* Q3     = (unsigned short*)(ws);                 // 22,282,240 B (reused as samp3)
  unsigned short* IFh    = (unsigned short*)(ws + 22282240);      // 11,141,120
  unsigned short* valb   = (unsigned short*)(ws + 33423360);      // 11,141,120
  float*          offb   = (float*)(ws + 44564480);               // 22,282,240
  unsigned short* logitb = (unsigned short*)(ws + 66846720);      //  5,570,560
  unsigned short* Woff2  = (unsigned short*)(ws + 72417280);      //    262,144
  unsigned short* Wo2    = (unsigned short*)(ws + 72679424);      //    262,144
  unsigned short* Wvt    = (unsigned short*)(ws + 72941568);      //    131,072
  unsigned short* Wat    = (unsigned short*)(ws + 73072640);      //     65,536
  unsigned short* samp3  = Q3;  // Q3 dead after the off/logit GEMMs

  dim3 blk(256);
  conv_inputs<<<dim3(M_TOT / 4), blk, 0, stream>>>(query, input_flatten, Q3, IFh);
  conv_weights<<<dim3(4, 14), blk, 0, stream>>>(w_off, w_out, w_val, w_attn, Woff2, Wo2, Wvt, Wat);
  // value = IFh @ w_val (plain bf16), out bf16
  gemm_mfma<4, (1 << 20), true><<<dim3(2, M_TOT / 128), blk, 0, stream>>>(
      IFh, 256, Wvt, b_val, (void*)valb, 256);
  // off = [Q_hi|Q_lo] @ [Wt_hi|Wt_hi], K=512, out f32
  gemm_mfma<8, (1 << 20), false><<<dim3(2, M_TOT / 128), blk, 0, stream>>>(
      Q3, 512, Woff2, b_off, (void*)offb, 256);
  // logits = Q_hi @ w_attn (plain bf16), out bf16
  gemm_mfma<4, (1 << 20), true><<<dim3(1, M_TOT / 128), blk, 0, stream>>>(
      Q3, 512, Wat, b_attn, (void*)logitb, 128);
  msda_sample_v4<<<dim3(M_TOT / 8), blk, 0, stream>>>(
      offb, logitb, valb, ref_pts, sshapes, lstart, samp3);
  // out = [samp_hi|samp_lo] @ [Wo_hi|Wo_hi], K=512, out f32
  gemm_mfma<8, (1 << 20), false><<<dim3(2, M_TOT / 128), blk, 0, stream>>>(
      samp3, 512, Wo2, b_out, (void*)out, 256);
}

// Round 5
// 116.859 us; speedup vs baseline: 1.6584x; 1.6584x over previous
//
#include <hip/hip_runtime.h>
#include <math.h>

#define N_HEADS 8
#define N_LEVELS 4
#define N_POINTS 4
#define LQ 5440
#define LV 5440
#define BATCH_ 4
#define M_TOT (BATCH_ * LQ)   // 21760

typedef __bf16 bf16x8 __attribute__((ext_vector_type(8)));
typedef float f32x4 __attribute__((ext_vector_type(4)));
typedef unsigned int uint_t;

__device__ __forceinline__ unsigned short rne_bf16(float x) {
  uint_t u = __float_as_uint(x);
  uint_t r = u + 0x7fffu + ((u >> 16) & 1u);
  return (unsigned short)(r >> 16);
}
__device__ __forceinline__ float bf16_to_f(unsigned short h) {
  return __uint_as_float(((uint_t)h) << 16);
}

// ---------------- input conversion: query -> Q3 (hi|lo), input_flatten -> IFh ----------------
__global__ __launch_bounds__(256) void conv_inputs(
    const float* __restrict__ q, const float* __restrict__ iff,
    unsigned short* __restrict__ Q3, unsigned short* __restrict__ IFh)
{
  const int t = blockIdx.x * 256 + threadIdx.x;   // 0 .. M*64
  const int r = t >> 6;
  const int c = (t & 63) * 4;
  const float4 qa = *(const float4*)(q + (size_t)r * 256 + c);
  ushort4 h, l;
  {
    const float v[4] = {qa.x, qa.y, qa.z, qa.w};
    unsigned short hh[4], ll[4];
#pragma unroll
    for (int i = 0; i < 4; ++i) {
      hh[i] = rne_bf16(v[i]);
      ll[i] = rne_bf16(v[i] - bf16_to_f(hh[i]));
    }
    h = make_ushort4(hh[0], hh[1], hh[2], hh[3]);
    l = make_ushort4(ll[0], ll[1], ll[2], ll[3]);
  }
  *(ushort4*)(Q3 + (size_t)r * 512 + c) = h;
  *(ushort4*)(Q3 + (size_t)r * 512 + 256 + c) = l;
  const float4 fa = *(const float4*)(iff + (size_t)r * 256 + c);
  *(ushort4*)(IFh + (size_t)r * 256 + c) =
      make_ushort4(rne_bf16(fa.x), rne_bf16(fa.y), rne_bf16(fa.z), rne_bf16(fa.w));
}

// ---------------- weight conversion (transpose + bf16) ----------------
// mode 1 (2-term split): Wt2[n][0..255]=hi, [256..511]=hi  (pairs with A=[hi|lo])
// mode 0: Wt[n][0..255]=hi
__global__ __launch_bounds__(256) void conv_weights(
    const float* __restrict__ w_off, const float* __restrict__ w_out,
    const float* __restrict__ w_val, const float* __restrict__ w_attn,
    unsigned short* __restrict__ Woff2, unsigned short* __restrict__ Wo2,
    unsigned short* __restrict__ Wvt, unsigned short* __restrict__ Wat)
{
  __shared__ float tbuf[64][65];
  const int tid = threadIdx.x;
  const int k0 = blockIdx.x * 64;
  const int yy = blockIdx.y;
  const float* src; unsigned short* dst; int N; int mode; int ntile;
  if (yy < 4)       { src = w_off;  dst = Woff2; N = 256; mode = 1; ntile = yy; }
  else if (yy < 8)  { src = w_out;  dst = Wo2;   N = 256; mode = 1; ntile = yy - 4; }
  else if (yy < 12) { src = w_val;  dst = Wvt;   N = 256; mode = 0; ntile = yy - 8; }
  else              { src = w_attn; dst = Wat;   N = 128; mode = 0; ntile = yy - 12; }
  const int n0 = ntile * 64;
#pragma unroll
  for (int i = 0; i < 16; ++i) {
    const int r = (tid >> 6) + i * 4;
    const int c = tid & 63;
    tbuf[r][c] = src[(size_t)(k0 + r) * N + n0 + c];
  }
  __syncthreads();
#pragma unroll
  for (int i = 0; i < 16; ++i) {
    const int n = (tid >> 6) + i * 4;
    const int kk = tid & 63;
    const float v = tbuf[kk][n];
    const unsigned short h = rne_bf16(v);
    if (mode) {
      const size_t rowb = (size_t)(n0 + n) * 512;
      dst[rowb + k0 + kk] = h;
      dst[rowb + 256 + k0 + kk] = h;
    } else {
      dst[(size_t)(n0 + n) * 256 + k0 + kk] = h;
    }
  }
}

// ---------------- bf16 MFMA GEMM, m97 structure ----------------
template<int KSTEPS, int AMOD, bool OUT_BF16>
__global__ __launch_bounds__(256) void gemm_mfma(
    const unsigned short* __restrict__ A, int lda,
    const unsigned short* __restrict__ Bt,   // [N][KSTEPS*64]
    const float* __restrict__ bias,
    void* __restrict__ Cout, int ldc)
{
  constexpr int LDB = KSTEPS * 64;
  __shared__ unsigned short As[128 * 64];
  __shared__ unsigned short Bs[128 * 64];
  const int tid = threadIdx.x;
  const int w = tid >> 6, lane = tid & 63;
  const int wm = w >> 1, wn = w & 1;
  const int lr = lane & 15, lk = lane >> 4;
  const int m0 = blockIdx.y * 128, n0 = blockIdx.x * 128;

  f32x4 acc[4][4] = {};

  for (int t = 0; t < KSTEPS; ++t) {
    int ka = t * 64; if (ka >= AMOD) ka -= AMOD;
    const int kb = t * 64;
#pragma unroll
    for (int i = 0; i < 4; ++i) {
      const int rbase = i * 32 + w * 8;
      const int row = rbase + (lane >> 3);
      const int slot = lane & 7;
      const int gs = slot ^ (row & 7);                 // inverse-swizzle the SOURCE (rule 21)
      const unsigned short* gp = A + (size_t)(m0 + row) * lda + ka + gs * 8;
      __builtin_amdgcn_global_load_lds(
          (const __attribute__((address_space(1))) uint_t*)gp,
          (__attribute__((address_space(3))) uint_t*)(As + rbase * 64), 16, 0, 0);
    }
#pragma unroll
    for (int i = 0; i < 4; ++i) {
      const int rbase = i * 32 + w * 8;
      const int row = rbase + (lane >> 3);
      const int slot = lane & 7;
      const int gs = slot ^ (row & 7);
      const unsigned short* gp = Bt + (size_t)(n0 + row) * LDB + kb + gs * 8;
      __builtin_amdgcn_global_load_lds(
          (const __attribute__((address_space(1))) uint_t*)gp,
          (__attribute__((address_space(3))) uint_t*)(Bs + rbase * 64), 16, 0, 0);
    }
    asm volatile("s_waitcnt vmcnt(0)" ::: "memory");
    __syncthreads();
#pragma unroll
    for (int kk = 0; kk < 2; ++kk) {
      bf16x8 af[4], bfv[4];
#pragma unroll
      for (int m = 0; m < 4; ++m) {
        const int row = wm * 64 + m * 16 + lr;
        const int so = (kk * 4 + lk) ^ (row & 7);      // swizzled read
        af[m] = *(const bf16x8*)((const char*)As + row * 128 + so * 16);
      }
#pragma unroll
      for (int n = 0; n < 4; ++n) {
        const int row = wn * 64 + n * 16 + lr;
        const int so = (kk * 4 + lk) ^ (row & 7);
        bfv[n] = *(const bf16x8*)((const char*)Bs + row * 128 + so * 16);
      }
#pragma unroll
      for (int m = 0; m < 4; ++m)
#pragma unroll
        for (int n = 0; n < 4; ++n)
          acc[m][n] = __builtin_amdgcn_mfma_f32_16x16x32_bf16(af[m], bfv[n], acc[m][n], 0, 0, 0);
    }
    __syncthreads();
  }
#pragma unroll
  for (int n = 0; n < 4; ++n) {
    const int col = n0 + wn * 64 + n * 16 + lr;
    const float bv = bias[col];
#pragma unroll
    for (int m = 0; m < 4; ++m) {
      const int rbase = m0 + wm * 64 + m * 16 + lk * 4;
#pragma unroll
      for (int j = 0; j < 4; ++j) {
        const float v = acc[m][n][j] + bv;
        if (OUT_BF16) ((unsigned short*)Cout)[(size_t)(rbase + j) * ldc + col] = rne_bf16(v);
        else          ((float*)Cout)[(size_t)(rbase + j) * ldc + col] = v;
      }
    }
  }
}

// ---------------- sampler v5: two-phase (LDS weight exchange) ----------------
// Block = 256 threads = 8 queries. Phase 1: lane=(q,h,l) computes its level's 4
// points' weights+byte-offsets with NO redundancy (coop softmax over 4 lanes),
// stores to LDS. Phase 2: lane=(q,h,dg) does v3-style gather+fma over its 8
// channels, reading weights/offsets via ds_read_b128 (acc[8] keeps VGPR low).
// LDS row per (q,h): 16 points x 8 dwords + 4 pad = 132 dwords (528B, 16B-aligned,
// bank-stagger 4 -> phase-2 reads are 2-way conflicts only).
__global__ __launch_bounds__(256) void msda_sample_v5(
    const float* __restrict__ off_buf,            // [M,256]
    const unsigned short* __restrict__ logit_buf, // [M,128] bf16
    const unsigned short* __restrict__ value,     // [B,LV,256] bf16
    const float* __restrict__ ref_pts,            // [B,LQ,4,2]
    const int*  __restrict__ sshapes, const int* __restrict__ lstart,
    unsigned short* __restrict__ samp3)           // [M,512]
{
  __shared__ uint_t wlds[64 * 132];               // 33,792 B
  const int tid = threadIdx.x;
  const int q0 = blockIdx.x * 8;
  const int b  = blockIdx.x / (LQ / 8);
  const int q  = tid >> 5;
  const int qg = q0 + q;

  // ---------- phase 1: lane = (q, h, l) ----------
  {
    const int h  = (tid >> 2) & 7;
    const int l  = tid & 3;
    const int Hl = sshapes[2 * l], Wl = sshapes[2 * l + 1];
    const int st = lstart[l];
    const float rx = ref_pts[(size_t)qg * 8 + l * 2 + 0];
    const float ry = ref_pts[(size_t)qg * 8 + l * 2 + 1];
    const float fx = rx * (float)Wl - 0.5f;
    const float fy = ry * (float)Hl - 0.5f;

    // 8 offsets for this (h,l): two float4s, coalesced
    const float* ob = off_buf + (size_t)qg * 256 + h * 32 + l * 8;
    const float4 o0 = *(const float4*)(ob);
    const float4 o1 = *(const float4*)(ob + 4);
    const float offv[8] = {o0.x, o0.y, o0.z, o0.w, o1.x, o1.y, o1.z, o1.w};

    // 4 logits: 8B coalesced
    const uint2 lgu = *(const uint2*)(logit_buf + (size_t)qg * 128 + h * 16 + l * 4);
    float lg[4];
    lg[0] = __uint_as_float(lgu.x << 16);
    lg[1] = __uint_as_float(lgu.x & 0xffff0000u);
    lg[2] = __uint_as_float(lgu.y << 16);
    lg[3] = __uint_as_float(lgu.y & 0xffff0000u);

    // cooperative softmax over the 16 logits of (q,h) (4 lanes x 4)
    float mx = fmaxf(fmaxf(lg[0], lg[1]), fmaxf(lg[2], lg[3]));
    mx = fmaxf(mx, __shfl_xor(mx, 1));
    mx = fmaxf(mx, __shfl_xor(mx, 2));
    float ex[4]; float ssum = 0.f;
#pragma unroll
    for (int p = 0; p < 4; ++p) { ex[p] = __expf(lg[p] - mx); ssum += ex[p]; }
    ssum += __shfl_xor(ssum, 1);
    ssum += __shfl_xor(ssum, 2);
    const float inv = 1.f / ssum;

    const uint_t base_l = ((uint_t)b * LV + (uint_t)st) * 512u + (uint_t)h * 64u;
    uint_t* wrow = wlds + (size_t)(q * 8 + h) * 132;

#pragma unroll
    for (int p = 0; p < 4; ++p) {
      const float x = fx + offv[p * 2 + 0];
      const float y = fy + offv[p * 2 + 1];
      const float aw = ex[p] * inv;
      const float xf = floorf(x), yf = floorf(y);
      const int x0i = (int)xf, y0i = (int)yf;
      const float wx1 = x - xf, wy1 = y - yf;
      const float wx0 = 1.f - wx1, wy0 = 1.f - wy1;
      const int x1i = x0i + 1, y1i = y0i + 1;
      const bool vx0 = (uint_t)x0i < (uint_t)Wl, vx1 = (uint_t)x1i < (uint_t)Wl;
      const bool vy0 = (uint_t)y0i < (uint_t)Hl, vy1 = (uint_t)y1i < (uint_t)Hl;
      const int xc0 = min(max(x0i, 0), Wl - 1), xc1 = min(max(x1i, 0), Wl - 1);
      const int yc0 = min(max(y0i, 0), Hl - 1), yc1 = min(max(y1i, 0), Hl - 1);
      const float awy0 = aw * wy0, awy1 = aw * wy1;
      float4 wv;
      wv.x = (vy0 && vx0) ? awy0 * wx0 : 0.f;
      wv.y = (vy0 && vx1) ? awy0 * wx1 : 0.f;
      wv.z = (vy1 && vx0) ? awy1 * wx0 : 0.f;
      wv.w = (vy1 && vx1) ? awy1 * wx1 : 0.f;
      const int r0 = yc0 * Wl, r1 = yc1 * Wl;
      uint4 vo;
      vo.x = base_l + (uint_t)(r0 + xc0) * 512u;
      vo.y = base_l + (uint_t)(r0 + xc1) * 512u;
      vo.z = base_l + (uint_t)(r1 + xc0) * 512u;
      vo.w = base_l + (uint_t)(r1 + xc1) * 512u;
      const int pi = l * 4 + p;
      *(float4*)(wrow + pi * 8)     = wv;
      *(uint4*)(wrow + pi * 8 + 4)  = vo;
    }
  }
  __syncthreads();

  // ---------- phase 2: lane = (q, h, dg) ----------
  const int h  = (tid >> 2) & 7;
  const int dg = tid & 3;
  const uint_t* wrow = wlds + (size_t)(q * 8 + h) * 132;
  const char* vbyte = (const char*)value + dg * 16;   // fold channel offset into base
  float acc[8] = {};

#define ACCUM8V(U4, WV) {                                                          \
    const uint_t uu0 = (U4).x, uu1 = (U4).y, uu2 = (U4).z, uu3 = (U4).w;           \
    acc[0] = fmaf((WV), __uint_as_float(uu0 << 16),         acc[0]);               \
    acc[1] = fmaf((WV), __uint_as_float(uu0 & 0xffff0000u), acc[1]);               \
    acc[2] = fmaf((WV), __uint_as_float(uu1 << 16),         acc[2]);               \
    acc[3] = fmaf((WV), __uint_as_float(uu1 & 0xffff0000u), acc[3]);               \
    acc[4] = fmaf((WV), __uint_as_float(uu2 << 16),         acc[4]);               \
    acc[5] = fmaf((WV), __uint_as_float(uu2 & 0xffff0000u), acc[5]);               \
    acc[6] = fmaf((WV), __uint_as_float(uu3 << 16),         acc[6]);               \
    acc[7] = fmaf((WV), __uint_as_float(uu3 & 0xffff0000u), acc[7]); }

#pragma unroll
  for (int pt = 0; pt < 16; ++pt) {
    const float4 wv = *(const float4*)(wrow + pt * 8);
    const uint4  vo = *(const uint4*)(wrow + pt * 8 + 4);
    { const uint4 g = *(const uint4*)(vbyte + vo.x); ACCUM8V(g, wv.x); }
    { const uint4 g = *(const uint4*)(vbyte + vo.y); ACCUM8V(g, wv.y); }
    { const uint4 g = *(const uint4*)(vbyte + vo.z); ACCUM8V(g, wv.z); }
    { const uint4 g = *(const uint4*)(vbyte + vo.w); ACCUM8V(g, wv.w); }
  }

  unsigned short h8[8], l8[8];
#pragma unroll
  for (int i = 0; i < 8; ++i) {
    h8[i] = rne_bf16(acc[i]);
    l8[i] = rne_bf16(acc[i] - bf16_to_f(h8[i]));
  }
  unsigned short* op = samp3 + (size_t)qg * 512 + h * 32 + dg * 8;
  *(ushort4*)(op)       = make_ushort4(h8[0], h8[1], h8[2], h8[3]);
  *(ushort4*)(op + 4)   = make_ushort4(h8[4], h8[5], h8[6], h8[7]);
  *(ushort4*)(op + 256) = make_ushort4(l8[0], l8[1], l8[2], l8[3]);
  *(ushort4*)(op + 260) = make_ushort4(l8[4], l8[5], l8[6], l8[7]);
}

extern "C" void kernel_launch(void* const* d_in, const int* in_sizes, int n_in,
                              void* d_out, int out_size, void* d_ws, size_t ws_size,
                              hipStream_t stream) {
  const float* query         = (const float*)d_in[0];
  const float* ref_pts       = (const float*)d_in[1];
  const float* input_flatten = (const float*)d_in[2];
  const int*   sshapes       = (const int*)d_in[3];
  const int*   lstart        = (const int*)d_in[4];
  const float* w_val  = (const float*)d_in[5];
  const float* b_val  = (const float*)d_in[6];
  const float* w_off  = (const float*)d_in[7];
  const float* b_off  = (const float*)d_in[8];
  const float* w_attn = (const float*)d_in[9];
  const float* b_attn = (const float*)d_in[10];
  const float* w_out  = (const float*)d_in[11];
  const float* b_out  = (const float*)d_in[12];
  float* out = (float*)d_out;

  char* ws = (char*)d_ws;
  unsigned short* Q3     = (unsigned short*)(ws);                 // 22,282,240 B (reused as samp3)
  unsigned short* IFh    = (unsigned short*)(ws + 22282240);      // 11,141,120
  unsigned short* valb   = (unsigned short*)(ws + 33423360);      // 11,141,120
  float*          offb   = (float*)(ws + 44564480);               // 22,282,240
  unsigned short* logitb = (unsigned short*)(ws + 66846720);      //  5,570,560
  unsigned short* Woff2  = (unsigned short*)(ws + 72417280);      //    262,144
  unsigned short* Wo2    = (unsigned short*)(ws + 72679424);      //    262,144
  unsigned short* Wvt    = (unsigned short*)(ws + 72941568);      //    131,072
  unsigned short* Wat    = (unsigned short*)(ws + 73072640);      //     65,536
  unsigned short* samp3  = Q3;  // Q3 dead after the off/logit GEMMs

  dim3 blk(256);
  conv_inputs<<<dim3(M_TOT / 4), blk, 0, stream>>>(query, input_flatten, Q3, IFh);
  conv_weights<<<dim3(4, 14), blk, 0, stream>>>(w_off, w_out, w_val, w_attn, Woff2, Wo2, Wvt, Wat);
  // value = IFh @ w_val (plain bf16), out bf16
  gemm_mfma<4, (1 << 20), true><<<dim3(2, M_TOT / 128), blk, 0, stream>>>(
      IFh, 256, Wvt, b_val, (void*)valb, 256);
  // off = [Q_hi|Q_lo] @ [Wt_hi|Wt_hi], K=512, out f32
  gemm_mfma<8, (1 << 20), false><<<dim3(2, M_TOT / 128), blk, 0, stream>>>(
      Q3, 512, Woff2, b_off, (void*)offb, 256);
  // logits = Q_hi @ w_attn (plain bf16), out bf16
  gemm_mfma<4, (1 << 20), true><<<dim3(1, M_TOT / 128), blk, 0, stream>>>(
      Q3, 512, Wat, b_attn, (void*)logitb, 128);
  msda_sample_v5<<<dim3(M_TOT / 8), blk, 0, stream>>>(
      offb, logitb, valb, ref_pts, sshapes, lstart, samp3);
  // out = [samp_hi|samp_lo] @ [Wo_hi|Wo_hi], K=512, out f32
  gemm_mfma<8, (1 << 20), false><<<dim3(2, M_TOT / 128), blk, 0, stream>>>(
      samp3, 512, Wo2, b_out, (void*)out, 256);
}

// Round 6
// 111.495 us; speedup vs baseline: 1.7382x; 1.0481x over previous
//
#include <hip/hip_runtime.h>
#include <hip/hip_fp16.h>
#include <math.h>

#define N_HEADS 8
#define N_LEVELS 4
#define N_POINTS 4
#define LQ 5440
#define LV 5440
#define BATCH_ 4
#define M_TOT (BATCH_ * LQ)   // 21760

typedef __bf16 bf16x8 __attribute__((ext_vector_type(8)));
typedef float f32x4 __attribute__((ext_vector_type(4)));
typedef unsigned int uint_t;

__device__ __forceinline__ unsigned short rne_bf16(float x) {
  uint_t u = __float_as_uint(x);
  uint_t r = u + 0x7fffu + ((u >> 16) & 1u);
  return (unsigned short)(r >> 16);
}
__device__ __forceinline__ float bf16_to_f(unsigned short h) {
  return __uint_as_float(((uint_t)h) << 16);
}
__device__ __forceinline__ uint_t f2h2(float a, float b) {   // pack 2 f32 -> half2 (RNE)
  const unsigned short ua = __half_as_ushort(__float2half(a));
  const unsigned short ub = __half_as_ushort(__float2half(b));
  return (uint_t)ua | ((uint_t)ub << 16);
}
__device__ __forceinline__ float h_lo(uint_t u) {
  return __half2float(__ushort_as_half((unsigned short)(u & 0xffffu)));
}
__device__ __forceinline__ float h_hi(uint_t u) {
  return __half2float(__ushort_as_half((unsigned short)(u >> 16)));
}

// ---------------- input conversion: query -> Q3 (hi|lo), input_flatten -> IFh ----------------
__global__ __launch_bounds__(256) void conv_inputs(
    const float* __restrict__ q, const float* __restrict__ iff,
    unsigned short* __restrict__ Q3, unsigned short* __restrict__ IFh)
{
  const int t = blockIdx.x * 256 + threadIdx.x;   // 0 .. M*64
  const int r = t >> 6;
  const int c = (t & 63) * 4;
  const float4 qa = *(const float4*)(q + (size_t)r * 256 + c);
  ushort4 h, l;
  {
    const float v[4] = {qa.x, qa.y, qa.z, qa.w};
    unsigned short hh[4], ll[4];
#pragma unroll
    for (int i = 0; i < 4; ++i) {
      hh[i] = rne_bf16(v[i]);
      ll[i] = rne_bf16(v[i] - bf16_to_f(hh[i]));
    }
    h = make_ushort4(hh[0], hh[1], hh[2], hh[3]);
    l = make_ushort4(ll[0], ll[1], ll[2], ll[3]);
  }
  *(ushort4*)(Q3 + (size_t)r * 512 + c) = h;
  *(ushort4*)(Q3 + (size_t)r * 512 + 256 + c) = l;
  const float4 fa = *(const float4*)(iff + (size_t)r * 256 + c);
  *(ushort4*)(IFh + (size_t)r * 256 + c) =
      make_ushort4(rne_bf16(fa.x), rne_bf16(fa.y), rne_bf16(fa.z), rne_bf16(fa.w));
}

// ---------------- weight conversion (transpose + bf16) ----------------
// mode 1 (2-term split): W[n][0..255]=hi, [256..511]=hi  (pairs with A=[hi|lo])
// mode 0: Wt[n][0..255]=hi
// Wcat: rows 0..255 = w_off, rows 256..383 = w_attn (both mode 1)
__global__ __launch_bounds__(256) void conv_weights(
    const float* __restrict__ w_off, const float* __restrict__ w_out,
    const float* __restrict__ w_val, const float* __restrict__ w_attn,
    unsigned short* __restrict__ Wcat, unsigned short* __restrict__ Wo2,
    unsigned short* __restrict__ Wvt)
{
  __shared__ float tbuf[64][65];
  const int tid = threadIdx.x;
  const int k0 = blockIdx.x * 64;
  const int yy = blockIdx.y;
  const float* src; unsigned short* dst; int N; int mode; int ntile; int roff = 0;
  if (yy < 4)       { src = w_off;  dst = Wcat; N = 256; mode = 1; ntile = yy; }
  else if (yy < 8)  { src = w_out;  dst = Wo2;  N = 256; mode = 1; ntile = yy - 4; }
  else if (yy < 12) { src = w_val;  dst = Wvt;  N = 256; mode = 0; ntile = yy - 8; }
  else              { src = w_attn; dst = Wcat; N = 128; mode = 1; ntile = yy - 12; roff = 256; }
  const int n0 = ntile * 64;
#pragma unroll
  for (int i = 0; i < 16; ++i) {
    const int r = (tid >> 6) + i * 4;
    const int c = tid & 63;
    tbuf[r][c] = src[(size_t)(k0 + r) * N + n0 + c];
  }
  __syncthreads();
#pragma unroll
  for (int i = 0; i < 16; ++i) {
    const int n = (tid >> 6) + i * 4;
    const int kk = tid & 63;
    const float v = tbuf[kk][n];
    const unsigned short h = rne_bf16(v);
    if (mode) {
      const size_t rowb = (size_t)(roff + n0 + n) * 512;
      dst[rowb + k0 + kk] = h;
      dst[rowb + 256 + k0 + kk] = h;
    } else {
      dst[(size_t)(n0 + n) * 256 + k0 + kk] = h;
    }
  }
}

// ---------------- bf16 MFMA GEMM, m97 structure ----------------
// MODE: 0 = f32 out, 1 = bf16 out, 2 = mixed (col<256 -> f32 C1 ldc 256; col>=256 -> bf16 C2 ldc 128)
template<int KSTEPS, int MODE>
__global__ __launch_bounds__(256) void gemm_mfma(
    const unsigned short* __restrict__ A, int lda,
    const unsigned short* __restrict__ Bt,   // [N][KSTEPS*64]
    const float* __restrict__ bias, const float* __restrict__ bias2,
    void* __restrict__ C1, int ldc, void* __restrict__ C2)
{
  constexpr int LDB = KSTEPS * 64;
  __shared__ unsigned short As[128 * 64];
  __shared__ unsigned short Bs[128 * 64];
  const int tid = threadIdx.x;
  const int w = tid >> 6, lane = tid & 63;
  const int wm = w >> 1, wn = w & 1;
  const int lr = lane & 15, lk = lane >> 4;
  const int m0 = blockIdx.y * 128, n0 = blockIdx.x * 128;

  f32x4 acc[4][4] = {};

  for (int t = 0; t < KSTEPS; ++t) {
    const int ka = t * 64;
#pragma unroll
    for (int i = 0; i < 4; ++i) {
      const int rbase = i * 32 + w * 8;
      const int row = rbase + (lane >> 3);
      const int slot = lane & 7;
      const int gs = slot ^ (row & 7);                 // inverse-swizzle the SOURCE (rule 21)
      const unsigned short* gp = A + (size_t)(m0 + row) * lda + ka + gs * 8;
      __builtin_amdgcn_global_load_lds(
          (const __attribute__((address_space(1))) uint_t*)gp,
          (__attribute__((address_space(3))) uint_t*)(As + rbase * 64), 16, 0, 0);
    }
#pragma unroll
    for (int i = 0; i < 4; ++i) {
      const int rbase = i * 32 + w * 8;
      const int row = rbase + (lane >> 3);
      const int slot = lane & 7;
      const int gs = slot ^ (row & 7);
      const unsigned short* gp = Bt + (size_t)(n0 + row) * LDB + ka + gs * 8;
      __builtin_amdgcn_global_load_lds(
          (const __attribute__((address_space(1))) uint_t*)gp,
          (__attribute__((address_space(3))) uint_t*)(Bs + rbase * 64), 16, 0, 0);
    }
    asm volatile("s_waitcnt vmcnt(0)" ::: "memory");
    __syncthreads();
#pragma unroll
    for (int kk = 0; kk < 2; ++kk) {
      bf16x8 af[4], bfv[4];
#pragma unroll
      for (int m = 0; m < 4; ++m) {
        const int row = wm * 64 + m * 16 + lr;
        const int so = (kk * 4 + lk) ^ (row & 7);      // swizzled read
        af[m] = *(const bf16x8*)((const char*)As + row * 128 + so * 16);
      }
#pragma unroll
      for (int n = 0; n < 4; ++n) {
        const int row = wn * 64 + n * 16 + lr;
        const int so = (kk * 4 + lk) ^ (row & 7);
        bfv[n] = *(const bf16x8*)((const char*)Bs + row * 128 + so * 16);
      }
#pragma unroll
      for (int m = 0; m < 4; ++m)
#pragma unroll
        for (int n = 0; n < 4; ++n)
          acc[m][n] = __builtin_amdgcn_mfma_f32_16x16x32_bf16(af[m], bfv[n], acc[m][n], 0, 0, 0);
    }
    __syncthreads();
  }
#pragma unroll
  for (int n = 0; n < 4; ++n) {
    const int col = n0 + wn * 64 + n * 16 + lr;
    const float bv = (MODE == 2 && col >= 256) ? bias2[col - 256] : bias[col];
#pragma unroll
    for (int m = 0; m < 4; ++m) {
      const int rbase = m0 + wm * 64 + m * 16 + lk * 4;
#pragma unroll
      for (int j = 0; j < 4; ++j) {
        const float v = acc[m][n][j] + bv;
        const int row = rbase + j;
        if (MODE == 0) {
          ((float*)C1)[(size_t)row * ldc + col] = v;
        } else if (MODE == 1) {
          ((unsigned short*)C1)[(size_t)row * ldc + col] = rne_bf16(v);
        } else {
          if (col < 256) ((float*)C1)[(size_t)row * 256 + col] = v;
          else           ((unsigned short*)C2)[(size_t)row * 128 + (col - 256)] = rne_bf16(v);
        }
      }
    }
  }
}

// ---------------- sampler v6: two-phase, packed 16B/point LDS exchange ----------------
// Block = 256 threads = 8 queries. Phase 1: lane=(q,h,l) computes its level's 4
// points' weights (->half2 x2) + corner element-row indices (->u16 x4), one uint4
// per point in LDS. Phase 2: lane=(q,h,dg): one ds_read_b128 per point, gather
// 4 corners x 16B, fma into acc[8].
// LDS row per (q,h): 16 points x 4 dwords + 4 pad = 68 dwords; total 64*68*4 = 17408 B.
__global__ __launch_bounds__(256) void msda_sample_v6(
    const float* __restrict__ off_buf,            // [M,256]
    const unsigned short* __restrict__ logit_buf, // [M,128] bf16
    const unsigned short* __restrict__ value,     // [B,LV,256] bf16
    const float* __restrict__ ref_pts,            // [B,LQ,4,2]
    const int*  __restrict__ sshapes, const int* __restrict__ lstart,
    unsigned short* __restrict__ samp3)           // [M,512]
{
  __shared__ uint_t wlds[64 * 68];                // 17,408 B
  const int tid = threadIdx.x;
  const int q0 = blockIdx.x * 8;
  const int b  = blockIdx.x / (LQ / 8);
  const int q  = tid >> 5;
  const int qg = q0 + q;

  // ---------- phase 1: lane = (q, h, l) ----------
  {
    const int h  = (tid >> 2) & 7;
    const int l  = tid & 3;
    const int Hl = sshapes[2 * l], Wl = sshapes[2 * l + 1];
    const int st = lstart[l];
    const float rx = ref_pts[(size_t)qg * 8 + l * 2 + 0];
    const float ry = ref_pts[(size_t)qg * 8 + l * 2 + 1];
    const float fx = rx * (float)Wl - 0.5f;
    const float fy = ry * (float)Hl - 0.5f;

    const float* ob = off_buf + (size_t)qg * 256 + h * 32 + l * 8;
    const float4 o0 = *(const float4*)(ob);
    const float4 o1 = *(const float4*)(ob + 4);
    const float offv[8] = {o0.x, o0.y, o0.z, o0.w, o1.x, o1.y, o1.z, o1.w};

    const uint2 lgu = *(const uint2*)(logit_buf + (size_t)qg * 128 + h * 16 + l * 4);
    float lg[4];
    lg[0] = __uint_as_float(lgu.x << 16);
    lg[1] = __uint_as_float(lgu.x & 0xffff0000u);
    lg[2] = __uint_as_float(lgu.y << 16);
    lg[3] = __uint_as_float(lgu.y & 0xffff0000u);

    // cooperative softmax over the 16 logits of (q,h) (4 lanes x 4)
    float mx = fmaxf(fmaxf(lg[0], lg[1]), fmaxf(lg[2], lg[3]));
    mx = fmaxf(mx, __shfl_xor(mx, 1));
    mx = fmaxf(mx, __shfl_xor(mx, 2));
    float ex[4]; float ssum = 0.f;
#pragma unroll
    for (int p = 0; p < 4; ++p) { ex[p] = __expf(lg[p] - mx); ssum += ex[p]; }
    ssum += __shfl_xor(ssum, 1);
    ssum += __shfl_xor(ssum, 2);
    const float inv = 1.f / ssum;

    const uint_t base_idx = (uint_t)b * LV + (uint_t)st;   // element-row base (fits u16 range after +r+x)
    uint_t* wrow = wlds + (size_t)(q * 8 + h) * 68;

#pragma unroll
    for (int p = 0; p < 4; ++p) {
      const float x = fx + offv[p * 2 + 0];
      const float y = fy + offv[p * 2 + 1];
      const float aw = ex[p] * inv;
      const float xf = floorf(x), yf = floorf(y);
      const int x0i = (int)xf, y0i = (int)yf;
      const float wx1 = x - xf, wy1 = y - yf;
      const float wx0 = 1.f - wx1, wy0 = 1.f - wy1;
      const int x1i = x0i + 1, y1i = y0i + 1;
      const bool vx0 = (uint_t)x0i < (uint_t)Wl, vx1 = (uint_t)x1i < (uint_t)Wl;
      const bool vy0 = (uint_t)y0i < (uint_t)Hl, vy1 = (uint_t)y1i < (uint_t)Hl;
      const int xc0 = min(max(x0i, 0), Wl - 1), xc1 = min(max(x1i, 0), Wl - 1);
      const int yc0 = min(max(y0i, 0), Hl - 1), yc1 = min(max(y1i, 0), Hl - 1);
      const float awy0 = aw * wy0, awy1 = aw * wy1;
      const float w00 = (vy0 && vx0) ? awy0 * wx0 : 0.f;
      const float w01 = (vy0 && vx1) ? awy0 * wx1 : 0.f;
      const float w10 = (vy1 && vx0) ? awy1 * wx0 : 0.f;
      const float w11 = (vy1 && vx1) ? awy1 * wx1 : 0.f;
      const uint_t r0 = base_idx + (uint_t)(yc0 * Wl), r1 = base_idx + (uint_t)(yc1 * Wl);
      uint4 pk;
      pk.x = f2h2(w00, w01);
      pk.y = f2h2(w10, w11);
      pk.z = (r0 + (uint_t)xc0) | ((r0 + (uint_t)xc1) << 16);
      pk.w = (r1 + (uint_t)xc0) | ((r1 + (uint_t)xc1) << 16);
      *(uint4*)(wrow + (l * 4 + p) * 4) = pk;
    }
  }
  __syncthreads();

  // ---------- phase 2: lane = (q, h, dg) ----------
  const int h  = (tid >> 2) & 7;
  const int dg = tid & 3;
  const uint_t* wrow = wlds + (size_t)(q * 8 + h) * 68;
  const char* vbyte = (const char*)value + (uint_t)h * 64u + (uint_t)dg * 16u;
  float acc[8] = {};

#define ACCUM8V(U4, WV) {                                                          \
    const uint_t uu0 = (U4).x, uu1 = (U4).y, uu2 = (U4).z, uu3 = (U4).w;           \
    acc[0] = fmaf((WV), __uint_as_float(uu0 << 16),         acc[0]);               \
    acc[1] = fmaf((WV), __uint_as_float(uu0 & 0xffff0000u), acc[1]);               \
    acc[2] = fmaf((WV), __uint_as_float(uu1 << 16),         acc[2]);               \
    acc[3] = fmaf((WV), __uint_as_float(uu1 & 0xffff0000u), acc[3]);               \
    acc[4] = fmaf((WV), __uint_as_float(uu2 << 16),         acc[4]);               \
    acc[5] = fmaf((WV), __uint_as_float(uu2 & 0xffff0000u), acc[5]);               \
    acc[6] = fmaf((WV), __uint_as_float(uu3 << 16),         acc[6]);               \
    acc[7] = fmaf((WV), __uint_as_float(uu3 & 0xffff0000u), acc[7]); }

#pragma unroll
  for (int pt = 0; pt < 16; ++pt) {
    const uint4 pk = *(const uint4*)(wrow + pt * 4);
    const float w0 = h_lo(pk.x), w1 = h_hi(pk.x);
    const float w2 = h_lo(pk.y), w3 = h_hi(pk.y);
    const uint_t i0 = pk.z & 0xffffu, i1 = pk.z >> 16;
    const uint_t i2 = pk.w & 0xffffu, i3 = pk.w >> 16;
    { const uint4 g = *(const uint4*)(vbyte + (size_t)i0 * 512u); ACCUM8V(g, w0); }
    { const uint4 g = *(const uint4*)(vbyte + (size_t)i1 * 512u); ACCUM8V(g, w1); }
    { const uint4 g = *(const uint4*)(vbyte + (size_t)i2 * 512u); ACCUM8V(g, w2); }
    { const uint4 g = *(const uint4*)(vbyte + (size_t)i3 * 512u); ACCUM8V(g, w3); }
  }

  unsigned short h8[8], l8[8];
#pragma unroll
  for (int i = 0; i < 8; ++i) {
    h8[i] = rne_bf16(acc[i]);
    l8[i] = rne_bf16(acc[i] - bf16_to_f(h8[i]));
  }
  unsigned short* op = samp3 + (size_t)qg * 512 + h * 32 + dg * 8;
  *(ushort4*)(op)       = make_ushort4(h8[0], h8[1], h8[2], h8[3]);
  *(ushort4*)(op + 4)   = make_ushort4(h8[4], h8[5], h8[6], h8[7]);
  *(ushort4*)(op + 256) = make_ushort4(l8[0], l8[1], l8[2], l8[3]);
  *(ushort4*)(op + 260) = make_ushort4(l8[4], l8[5], l8[6], l8[7]);
}

extern "C" void kernel_launch(void* const* d_in, const int* in_sizes, int n_in,
                              void* d_out, int out_size, void* d_ws, size_t ws_size,
                              hipStream_t stream) {
  const float* query         = (const float*)d_in[0];
  const float* ref_pts       = (const float*)d_in[1];
  const float* input_flatten = (const float*)d_in[2];
  const int*   sshapes       = (const int*)d_in[3];
  const int*   lstart        = (const int*)d_in[4];
  const float* w_val  = (const float*)d_in[5];
  const float* b_val  = (const float*)d_in[6];
  const float* w_off  = (const float*)d_in[7];
  const float* b_off  = (const float*)d_in[8];
  const float* w_attn = (const float*)d_in[9];
  const float* b_attn = (const float*)d_in[10];
  const float* w_out  = (const float*)d_in[11];
  const float* b_out  = (const float*)d_in[12];
  float* out = (float*)d_out;

  char* ws = (char*)d_ws;
  unsigned short* Q3     = (unsigned short*)(ws);                 // 22,282,240 B (reused as samp3)
  unsigned short* IFh    = (unsigned short*)(ws + 22282240);      // 11,141,120
  unsigned short* valb   = (unsigned short*)(ws + 33423360);      // 11,141,120
  float*          offb   = (float*)(ws + 44564480);               // 22,282,240
  unsigned short* logitb = (unsigned short*)(ws + 66846720);      //  5,570,560
  unsigned short* Wcat   = (unsigned short*)(ws + 72417280);      //    393,216  [384][512]
  unsigned short* Wo2    = (unsigned short*)(ws + 72810496);      //    262,144  [256][512]
  unsigned short* Wvt    = (unsigned short*)(ws + 73072640);      //    131,072  [256][256]
  unsigned short* samp3  = Q3;  // Q3 dead after the fused off/logit GEMM

  dim3 blk(256);
  conv_inputs<<<dim3(M_TOT / 4), blk, 0, stream>>>(query, input_flatten, Q3, IFh);
  conv_weights<<<dim3(4, 14), blk, 0, stream>>>(w_off, w_out, w_val, w_attn, Wcat, Wo2, Wvt);
  // value = IFh @ w_val (plain bf16), out bf16
  gemm_mfma<4, 1><<<dim3(2, M_TOT / 128), blk, 0, stream>>>(
      IFh, 256, Wvt, b_val, nullptr, (void*)valb, 256, nullptr);
  // fused: [off | logits] = [Q_hi|Q_lo] @ Wcat^T, K=512, mixed epilogue
  gemm_mfma<8, 2><<<dim3(3, M_TOT / 128), blk, 0, stream>>>(
      Q3, 512, Wcat, b_off, b_attn, (void*)offb, 256, (void*)logitb);
  msda_sample_v6<<<dim3(M_TOT / 8), blk, 0, stream>>>(
      offb, logitb, valb, ref_pts, sshapes, lstart, samp3);
  // out = [samp_hi|samp_lo] @ [Wo_hi|Wo_hi], K=512, out f32
  gemm_mfma<8, 0><<<dim3(2, M_TOT / 128), blk, 0, stream>>>(
      samp3, 512, Wo2, b_out, nullptr, (void*)out, 256, nullptr);
}